// Round 14
// baseline (199.076 us; speedup 1.0000x reference)
//
#include <hip/hip_runtime.h>
#include <hip/hip_bf16.h>

// QLSTM: quantum layer collapses to products of cosines.
// qlayer(x,th) with c_w = cos(x_w+th_w): out = [c1c2c3, c0c1, c0c1c2, c0c1c2c3]
//
// R13: fusion retry. p1 (producer, t-major, 512 blocks) + p2 (consumer,
// 16 blocks x 8 waves, one batch-quad per wave) in ONE kernel.
// R11 failure was VGPR=36 spill-thrash; fixed with __launch_bounds__(512,2).
// Flags: per-(t,b-chunk), threadfence+agent-release / agent-acquire spin.

#define T_STEPS 128
#define BATCH 512
#define IDIM 512
#define FLAG_OFF (T_STEPS * BATCH * 20 * 4)   // 5242880 B: flag region in ws
#define N_FLAGS 512

typedef __attribute__((ext_vector_type(8))) short bf16x8;
typedef __attribute__((ext_vector_type(4))) float f32x4;

#define INV2PI 0.15915494309189535f
#define L2E    1.4426950408889634f

static __device__ __forceinline__ short bfbits(__hip_bfloat16 h) {
    union { __hip_bfloat16 b; short s; } c; c.b = h; return c.s;
}

// DPP: quad_perm xor1=0xB1 xor2=0x4E xor3=0x1B; row_ror:n = 0x120|n.
template<int CTRL>
static __device__ __forceinline__ float qperm(float v) {
    return __int_as_float(__builtin_amdgcn_update_dpp(
        0, __float_as_int(v), CTRL, 0xF, 0xF, true));
}

static __device__ __forceinline__ float frcp(float v) {
    return __builtin_amdgcn_rcpf(v);
}

// ---------------- Phase 1 body ----------------
// block bid covers rows [bid*128, bid*128+128): quarter (bid&3) of t=bid>>2.
static __device__ __forceinline__ void p1_body(
    int bid, int tid,
    const float* __restrict__ x,
    const float* __restrict__ Wf, const float* __restrict__ Wi,
    const float* __restrict__ Wu, const float* __restrict__ Wo,
    const float* __restrict__ kv,
    float* __restrict__ ws)
{
    __shared__ __align__(16) unsigned short whi[16 * 64 * 8];  // 16 KB
    __shared__ __align__(16) unsigned short wlo[16 * 64 * 8];  // 16 KB
    __shared__ __align__(16) float kvl[IDIM];                  // 2 KB

#pragma unroll
    for (int kk = 0; kk < 2; ++kk) {
        const int idx = tid + kk * 512;
        const int ks = idx >> 6;
        const int l  = idx & 63;
        const int c  = l & 15;
        const int bq = l >> 4;
        const int g  = c >> 2, q = c & 3;
        const float* Wsel = (g == 0) ? Wf : (g == 1) ? Wi : (g == 2) ? Wu : Wo;
        const float* src = Wsel + (size_t)q * 516 + ks * 32 + bq * 8;
        float4 w0 = *(const float4*)src;
        float4 w1 = *(const float4*)(src + 4);
        float wf8[8] = {w0.x, w0.y, w0.z, w0.w, w1.x, w1.y, w1.z, w1.w};
        unsigned short h8[8], l8[8];
#pragma unroll
        for (int j = 0; j < 8; ++j) {
            __hip_bfloat16 h = __float2bfloat16(wf8[j]);
            h8[j] = (unsigned short)bfbits(h);
            float r = wf8[j] - __bfloat162float(h);
            l8[j] = (unsigned short)bfbits(__float2bfloat16(r));
        }
        *(uint4*)&whi[idx * 8] = *(const uint4*)h8;
        *(uint4*)&wlo[idx * 8] = *(const uint4*)l8;
    }
    if (tid < 128)
        *(float4*)&kvl[tid * 4] = *(const float4*)(kv + tid * 4);
    __syncthreads();

    const int lane  = tid & 63;
    const int wave  = tid >> 6;
    const int row16 = lane & 15;
    const int kb    = lane >> 4;
    const int rowbase = (bid * 8 + wave) * 16;

    const float* xp = x + (size_t)(rowbase + row16) * IDIM + kb * 8;

    f32x4 acc = {0.f, 0.f, 0.f, 0.f};
    float d2 = 0.f;

    float4 pA[2], pB[2];
    pA[0] = *(const float4*)(xp);       pB[0] = *(const float4*)(xp + 4);
    pA[1] = *(const float4*)(xp + 32);  pB[1] = *(const float4*)(xp + 36);

#pragma unroll
    for (int ks = 0; ks < 16; ++ks) {
        const int sl = ks & 1;
        float xf[8] = {pA[sl].x, pA[sl].y, pA[sl].z, pA[sl].w,
                       pB[sl].x, pB[sl].y, pB[sl].z, pB[sl].w};
        if (ks + 2 < 16) {
            pA[sl] = *(const float4*)(xp + (ks + 2) * 32);
            pB[sl] = *(const float4*)(xp + (ks + 2) * 32 + 4);
        }

        const float* kvp = &kvl[ks * 32 + kb * 8];
        float4 kva = *(const float4*)kvp;
        float4 kvb = *(const float4*)(kvp + 4);
        float kvv[8] = {kva.x, kva.y, kva.z, kva.w, kvb.x, kvb.y, kvb.z, kvb.w};
#pragma unroll
        for (int j = 0; j < 8; ++j) {
            float dx = xf[j] - kvv[j];
            d2 = fmaf(dx, dx, d2);
        }

        bf16x8 ah, al;
#pragma unroll
        for (int j = 0; j < 8; ++j) {
            __hip_bfloat16 h = __float2bfloat16(xf[j]);
            ah[j] = bfbits(h);
            float r = xf[j] - __bfloat162float(h);
            al[j] = bfbits(__float2bfloat16(r));
        }

        bf16x8 wh = *(const bf16x8*)&whi[(ks * 64 + lane) * 8];
        bf16x8 wl = *(const bf16x8*)&wlo[(ks * 64 + lane) * 8];

        acc = __builtin_amdgcn_mfma_f32_16x16x32_bf16(ah, wh, acc, 0, 0, 0);
        acc = __builtin_amdgcn_mfma_f32_16x16x32_bf16(al, wh, acc, 0, 0, 0);
        acc = __builtin_amdgcn_mfma_f32_16x16x32_bf16(ah, wl, acc, 0, 0, 0);
    }

    d2 += __shfl_xor(d2, 16);
    d2 += __shfl_xor(d2, 32);

    const int ccol = lane & 15;
    const int crow = (lane >> 4) * 4;
#pragma unroll
    for (int j = 0; j < 4; ++j)
        ws[(size_t)(rowbase + crow + j) * 20 + ccol] = acc[j];
    if (lane < 16)
        ws[(size_t)(rowbase + lane) * 20 + 16] = d2;
}

// ---------------- Phase 2 body ----------------
// quad pb -> batches pb*4..pb*4+3; 16 lanes per batch element.
// flags != nullptr: spin on flags[t*4 + pb/32] before prefetching rows of t.
static __device__ __forceinline__ void p2_body(
    int pb, int lane,
    const float* __restrict__ ws,
    const float* __restrict__ Wf, const float* __restrict__ Wi,
    const float* __restrict__ Wu, const float* __restrict__ Wo,
    const float* __restrict__ bf, const float* __restrict__ bi,
    const float* __restrict__ bu, const float* __restrict__ bo,
    const float* __restrict__ thf, const float* __restrict__ thi,
    const float* __restrict__ thu, const float* __restrict__ tho,
    const float* __restrict__ kv,
    float* __restrict__ out,
    const int* flags)
{
    const int b    = pb * 4 + (lane >> 4);
    const int s    = lane & 15;
    const int g    = s >> 2;
    const int q    = s & 3;
    const int fc   = pb >> 5;

    const float* W  = (g == 0) ? Wf  : (g == 1) ? Wi  : (g == 2) ? Wu  : Wo;
    const float* bb = (g == 0) ? bf  : (g == 1) ? bi  : (g == 2) ? bu  : bo;
    const float* th = (g == 0) ? thf : (g == 1) ? thi : (g == 2) ? thu : tho;

    const float wh0 = W[(size_t)q * 516 + 512 + (q ^ 0)];
    const float wh1 = W[(size_t)q * 516 + 512 + (q ^ 1)];
    const float wh2 = W[(size_t)q * 516 + 512 + (q ^ 2)];
    const float wh3 = W[(size_t)q * 516 + 512 + (q ^ 3)];
    const float bias  = bb[q];
    const float threv = th[q] * INV2PI;
    const float kh0 = kv[512 + (q ^ 0)];
    const float kh1 = kv[512 + (q ^ 1)];
    const float kh2 = kv[512 + (q ^ 2)];
    const float kh3 = kv[512 + (q ^ 3)];

    const bool g0m = (g == 0), g1m = (g == 1), g2m = (g == 2);
    const bool q0m = (q == 0), q1m = (q == 1);
    const bool qodd = (q & 1);

    const float cz = g2m ? (-2.f * L2E) : (-L2E);
    const float vs = g2m ? 2.f : 1.f;
    const float vo = g2m ? -1.f : 0.f;

    float h0 = 0.f, h1 = 0.f, h2 = 0.f, h3 = 0.f, cx = 0.f;

    #define WS_SX(t) ws[((size_t)(t) * BATCH + b) * 20 + s]
    #define WS_D2(t) ws[((size_t)(t) * BATCH + b) * 20 + 16]
    #define WAITF(t) do { if (flags) {                                      \
        while (__hip_atomic_load(&flags[(t) * 4 + fc], __ATOMIC_ACQUIRE,    \
                                 __HIP_MEMORY_SCOPE_AGENT) == 0)            \
            __builtin_amdgcn_s_sleep(2);                                    \
    } } while (0)

    WAITF(0); WAITF(1); WAITF(2); WAITF(3);
    float cs0 = WS_SX(0), cd0 = WS_D2(0);
    float cs1 = WS_SX(1), cd1 = WS_D2(1);
    float cs2 = WS_SX(2), cd2 = WS_D2(2);
    float cs3 = WS_SX(3), cd3 = WS_D2(3);

    #define STEP(SX, D2X, t) do {                                          \
        float sxb = (SX) + bias;                                           \
        float gx  = __builtin_amdgcn_exp2f((D2X) * (-0.001f * L2E)) * INV2PI; \
        float dh0 = h0 - kh0, dh1 = h1 - kh1, dh2 = h2 - kh2, dh3 = h3 - kh3; \
        float d2h = fmaf(dh0, dh0, dh1 * dh1) + fmaf(dh2, dh2, dh3 * dh3); \
        float uu = d2h * 1.0e-3f;                                          \
        float pa = fmaf(-0.16666667f, uu, 0.5f);                           \
        float pc = fmaf(-uu, pa, 1.0f);                                    \
        float gh = fmaf(-uu, pc, 1.0f);                                    \
        float gater = gh * gx;                                             \
        float p01 = fmaf(wh1, h1, fmaf(wh0, h0, sxb));                     \
        float p23 = fmaf(wh3, h3, wh2 * h2);                               \
        float pre = p01 + p23;                                             \
        float rev = fmaf(pre, gater, threv);                               \
        float cang = __builtin_amdgcn_cosf(__builtin_amdgcn_fractf(rev));  \
        float s1 = qperm<0xB1>(cang);                                      \
        float s2 = qperm<0x4E>(cang);                                      \
        float s3 = qperm<0x1B>(cang);                                      \
        float m23 = s2 * s3;                                               \
        float A  = q0m ? s1 : cang;                                        \
        float T1 = qodd ? s1 : 1.f;                                        \
        float T2 = q1m ? 1.f : m23;                                        \
        float z = A * T1 * T2;                                             \
        float e  = __builtin_amdgcn_exp2f(z * cz);                         \
        float sg = frcp(1.f + e);                                          \
        float val = fmaf(vs, sg, vo);                                      \
        float r4  = qperm<0x124>(val);                                     \
        float r8  = qperm<0x128>(val);                                     \
        float r12 = qperm<0x12C>(val);                                     \
        float f_ = g0m ? val : g1m ? r4  : g2m ? r8  : r12;                \
        float i_ = g0m ? r12 : g1m ? val : g2m ? r4  : r8;                 \
        float u_ = g0m ? r8  : g1m ? r12 : g2m ? val : r4;                 \
        float o_ = g0m ? r4  : g1m ? r8  : g2m ? r12 : val;                \
        float cn = fmaf(f_, cx, i_ * u_);                                  \
        float e2 = __builtin_amdgcn_exp2f(cn * (-2.f * L2E));              \
        float thc = (1.f - e2) * frcp(1.f + e2);                           \
        float hn = o_ * thc;                                               \
        cx = cn;                                                           \
        h0 = hn;                                                           \
        h1 = qperm<0xB1>(hn);                                              \
        h2 = qperm<0x4E>(hn);                                              \
        h3 = qperm<0x1B>(hn);                                              \
        if (g0m) out[(size_t)(t) * (BATCH * 4) + b * 4 + q] = hn;          \
    } while (0)

    for (int tb = 0; tb < T_STEPS / 4; ++tb) {
        const int t0 = tb * 4;
        float ns0 = 0.f, nd0 = 0.f, ns1 = 0.f, nd1 = 0.f;
        float ns2 = 0.f, nd2 = 0.f, ns3 = 0.f, nd3 = 0.f;
        if (tb < T_STEPS / 4 - 1) {
            WAITF(t0 + 4); WAITF(t0 + 5); WAITF(t0 + 6); WAITF(t0 + 7);
            ns0 = WS_SX(t0 + 4); nd0 = WS_D2(t0 + 4);
            ns1 = WS_SX(t0 + 5); nd1 = WS_D2(t0 + 5);
            ns2 = WS_SX(t0 + 6); nd2 = WS_D2(t0 + 6);
            ns3 = WS_SX(t0 + 7); nd3 = WS_D2(t0 + 7);
        }
        STEP(cs0, cd0, t0 + 0);
        STEP(cs1, cd1, t0 + 1);
        STEP(cs2, cd2, t0 + 2);
        STEP(cs3, cd3, t0 + 3);
        cs0 = ns0; cd0 = nd0; cs1 = ns1; cd1 = nd1;
        cs2 = ns2; cd2 = nd2; cs3 = ns3; cd3 = nd3;
    }

    #undef STEP
    #undef WAITF
    #undef WS_SX
    #undef WS_D2

    if (g0m) {
        const size_t base = (size_t)T_STEPS * BATCH * 4;
        out[base + b * 4 + q] = h0;
        out[base + BATCH * 4 + b * 4 + q] = cx;
    }
}

// ---------------- Fused kernel ----------------
// blocks 0..511: producers (t-major p1). blocks 512..527: consumers,
// 8 waves each, one batch-quad per wave.
__global__ __launch_bounds__(512, 2) void qlstm_fused(
    const float* __restrict__ x,
    const float* __restrict__ Wf, const float* __restrict__ Wi,
    const float* __restrict__ Wu, const float* __restrict__ Wo,
    const float* __restrict__ bf, const float* __restrict__ bi,
    const float* __restrict__ bu, const float* __restrict__ bo,
    const float* __restrict__ thf, const float* __restrict__ thi,
    const float* __restrict__ thu, const float* __restrict__ tho,
    const float* __restrict__ kv,
    float* __restrict__ ws, float* __restrict__ out, int* flags)
{
    const int bid = blockIdx.x;
    if (bid < 512) {
        p1_body(bid, threadIdx.x, x, Wf, Wi, Wu, Wo, kv, ws);
        __syncthreads();                    // all waves' stores drained
        if (threadIdx.x == 0) {
            __threadfence();                // L2 writeback, cross-XCD vis
            __hip_atomic_store(&flags[bid], 1, __ATOMIC_RELEASE,
                               __HIP_MEMORY_SCOPE_AGENT);
        }
    } else {
        const int pb = (bid - 512) * 8 + (threadIdx.x >> 6);
        p2_body(pb, threadIdx.x & 63, ws, Wf, Wi, Wu, Wo,
                bf, bi, bu, bo, thf, thi, thu, tho, kv, out, flags);
    }
}

// ---------------- Serial fallback kernels ----------------
__global__ __launch_bounds__(512) void qlstm_p1(
    const float* __restrict__ x,
    const float* __restrict__ Wf, const float* __restrict__ Wi,
    const float* __restrict__ Wu, const float* __restrict__ Wo,
    const float* __restrict__ kv, float* __restrict__ ws)
{
    p1_body(blockIdx.x, threadIdx.x, x, Wf, Wi, Wu, Wo, kv, ws);
}

__global__ __launch_bounds__(64) void qlstm_p2(
    const float* __restrict__ ws,
    const float* __restrict__ Wf, const float* __restrict__ Wi,
    const float* __restrict__ Wu, const float* __restrict__ Wo,
    const float* __restrict__ bf, const float* __restrict__ bi,
    const float* __restrict__ bu, const float* __restrict__ bo,
    const float* __restrict__ thf, const float* __restrict__ thi,
    const float* __restrict__ thu, const float* __restrict__ tho,
    const float* __restrict__ kv, float* __restrict__ out)
{
    p2_body(blockIdx.x, threadIdx.x, ws, Wf, Wi, Wu, Wo,
            bf, bi, bu, bo, thf, thi, thu, tho, kv, out, nullptr);
}

extern "C" void kernel_launch(void* const* d_in, const int* in_sizes, int n_in,
                              void* d_out, int out_size, void* d_ws, size_t ws_size,
                              hipStream_t stream) {
    const float* x   = (const float*)d_in[0];
    const float* Wf  = (const float*)d_in[1];
    const float* bf  = (const float*)d_in[2];
    const float* Wi  = (const float*)d_in[3];
    const float* bi  = (const float*)d_in[4];
    const float* Wu  = (const float*)d_in[5];
    const float* bu  = (const float*)d_in[6];
    const float* Wo  = (const float*)d_in[7];
    const float* bo  = (const float*)d_in[8];
    const float* thf = (const float*)d_in[9];
    const float* thi = (const float*)d_in[10];
    const float* thu = (const float*)d_in[11];
    const float* tho = (const float*)d_in[12];
    const float* kv  = (const float*)d_in[13];
    float* out = (float*)d_out;
    float* ws  = (float*)d_ws;

    if (ws_size >= (size_t)FLAG_OFF + N_FLAGS * sizeof(int)) {
        int* flags = (int*)((char*)d_ws + FLAG_OFF);
        hipMemsetAsync(flags, 0, N_FLAGS * sizeof(int), stream);
        qlstm_fused<<<528, 512, 0, stream>>>(x, Wf, Wi, Wu, Wo, bf, bi, bu, bo,
                                             thf, thi, thu, tho, kv, ws, out, flags);
    } else {
        qlstm_p1<<<512, 512, 0, stream>>>(x, Wf, Wi, Wu, Wo, kv, ws);
        qlstm_p2<<<128, 64, 0, stream>>>(ws, Wf, Wi, Wu, Wo, bf, bi, bu, bo,
                                         thf, thi, thu, tho, kv, out);
    }
}

// Round 15
// 116.627 us; speedup vs baseline: 1.7069x; 1.7069x over previous
//
#include <hip/hip_runtime.h>
#include <hip/hip_bf16.h>

// QLSTM fused single-pass: each block computes its own sx tiles via MFMA in
// the recurrence's latency bubbles. No inter-block sync, no ws round-trip.
// qlayer(x,th) with c_w = cos(x_w+th_w): out = [c1c2c3, c0c1, c0c1c2, c0c1c2c3]
//
// p0: W -> bf16 hi/lo MFMA B-fragment table (32KB) in ws.
// fused: 128 blocks x 1 wave; 4 batches/block (16 lanes each).
//   Per t-quad: stage next quad's x rows via global_load_lds (dbuf),
//   MFMA 16x16 tile (split-bf16, 3 mfma x 16 ksteps), d2 in f32,
//   __shfl-redistribute (sx,d2) to recurrence lanes, then 4 chain steps.

#define T_STEPS 128
#define BATCH 512
#define IDIM 512
#define QSF (4 * BATCH * IDIM)     // floats per t-quad of x

typedef __attribute__((ext_vector_type(8))) short bf16x8;
typedef __attribute__((ext_vector_type(4))) float f32x4;

#define INV2PI 0.15915494309189535f
#define L2E    1.4426950408889634f

static __device__ __forceinline__ short bfbits(__hip_bfloat16 h) {
    union { __hip_bfloat16 b; short s; } c; c.b = h; return c.s;
}

// DPP: quad_perm xor1=0xB1 xor2=0x4E xor3=0x1B; row_ror:n = 0x120|n.
template<int CTRL>
static __device__ __forceinline__ float qperm(float v) {
    return __int_as_float(__builtin_amdgcn_update_dpp(
        0, __float_as_int(v), CTRL, 0xF, 0xF, true));
}
static __device__ __forceinline__ float frcp(float v) {
    return __builtin_amdgcn_rcpf(v);
}

#define GLOAD16(gp, lp)                                                     \
    __builtin_amdgcn_global_load_lds(                                       \
        (const __attribute__((address_space(1))) unsigned int*)(gp),        \
        (__attribute__((address_space(3))) unsigned int*)(lp), 16, 0, 0)

// ---------------- p0: W -> bf16 hi/lo fragment table in ws ----------------
// table: hi at bytes [0,16K): (ks*64+lane)*16; lo at [16K,32K).
__global__ __launch_bounds__(64) void qlstm_p0(
    const float* __restrict__ Wf, const float* __restrict__ Wi,
    const float* __restrict__ Wu, const float* __restrict__ Wo,
    float* __restrict__ ws)
{
    const int idx = blockIdx.x * 64 + threadIdx.x;   // 0..1023 = ks*64+lane
    const int ks = idx >> 6, l = idx & 63;
    const int c = l & 15, bq = l >> 4;
    const int g = c >> 2, q = c & 3;
    const float* Wsel = (g == 0) ? Wf : (g == 1) ? Wi : (g == 2) ? Wu : Wo;
    const float* src = Wsel + (size_t)q * 516 + ks * 32 + bq * 8;
    float4 w0 = *(const float4*)src;
    float4 w1 = *(const float4*)(src + 4);
    float wf8[8] = {w0.x, w0.y, w0.z, w0.w, w1.x, w1.y, w1.z, w1.w};
    unsigned short h8[8], l8[8];
#pragma unroll
    for (int j = 0; j < 8; ++j) {
        __hip_bfloat16 h = __float2bfloat16(wf8[j]);
        h8[j] = (unsigned short)bfbits(h);
        float r = wf8[j] - __bfloat162float(h);
        l8[j] = (unsigned short)bfbits(__float2bfloat16(r));
    }
    uint4* wt = (uint4*)ws;
    wt[idx]        = *(const uint4*)h8;
    wt[1024 + idx] = *(const uint4*)l8;
}

// ---------------- fused kernel ----------------
__global__ __launch_bounds__(64) void qlstm_fused(
    const float* __restrict__ x,
    const float* __restrict__ Wf, const float* __restrict__ Wi,
    const float* __restrict__ Wu, const float* __restrict__ Wo,
    const float* __restrict__ bf, const float* __restrict__ bi,
    const float* __restrict__ bu, const float* __restrict__ bo,
    const float* __restrict__ thf, const float* __restrict__ thi,
    const float* __restrict__ thu, const float* __restrict__ tho,
    const float* __restrict__ kv,
    const float* __restrict__ wt,     // p0's fragment table (32KB)
    float* __restrict__ out)
{
    __shared__ __align__(16) char xbA[32768];   // x quad dbuf A
    __shared__ __align__(16) char xbB[32768];   // x quad dbuf B
    __shared__ __align__(16) char wld[32768];   // W fragments hi|lo
    __shared__ __align__(16) char kvl[2048];    // kv[0..511] linear

    const int lane = threadIdx.x;
    const int blk  = blockIdx.x;
    // recurrence identity: 16 lanes per batch element
    const int s = lane & 15, g = s >> 2, q = s & 3;
    const int b = blk * 4 + (lane >> 4);
    // MFMA identity: A-frag row16 = tt*4+bb, k-chunk kb
    const int kb    = lane >> 4;
    const int row16 = lane & 15;
    const int tt_l  = row16 >> 2, bb_l = row16 & 3;

    // ---- issue all staging up front (async, zero VGPR) ----
    const char* wtl = (const char*)wt + lane * 16;
#pragma unroll
    for (int j = 0; j < 32; ++j)
        GLOAD16(wtl + j * 1024, wld + j * 1024);
    const char* kvp = (const char*)kv + lane * 16;
    GLOAD16(kvp,        kvl);
    GLOAD16(kvp + 1024, kvl + 1024);

    const float* px = x + ((size_t)tt_l * BATCH + blk * 4 + bb_l) * IDIM + kb * 8;

    #define XSTAGE(BUF, PX) do {                                            \
        _Pragma("unroll")                                                   \
        for (int j_ = 0; j_ < 32; ++j_) {                                   \
            const int ks_ = j_ >> 1, h_ = j_ & 1;                           \
            GLOAD16((const char*)(PX) + ks_ * 128 + h_ * 16,                \
                    BUF + j_ * 1024);                                       \
        }                                                                   \
    } while (0)

    XSTAGE(xbA, px);
    XSTAGE(xbB, px + QSF);
    px += 2 * (size_t)QSF;

    // ---- recurrence constants (xor-relative, per lane) ----
    const float* W  = (g == 0) ? Wf  : (g == 1) ? Wi  : (g == 2) ? Wu  : Wo;
    const float* bb_ = (g == 0) ? bf  : (g == 1) ? bi  : (g == 2) ? bu  : bo;
    const float* th = (g == 0) ? thf : (g == 1) ? thi : (g == 2) ? thu : tho;
    const float wh0 = W[(size_t)q * 516 + 512 + (q ^ 0)];
    const float wh1 = W[(size_t)q * 516 + 512 + (q ^ 1)];
    const float wh2 = W[(size_t)q * 516 + 512 + (q ^ 2)];
    const float wh3 = W[(size_t)q * 516 + 512 + (q ^ 3)];
    const float bias  = bb_[q];
    const float threv = th[q] * INV2PI;
    const float kh0 = kv[512 + (q ^ 0)];
    const float kh1 = kv[512 + (q ^ 1)];
    const float kh2 = kv[512 + (q ^ 2)];
    const float kh3 = kv[512 + (q ^ 3)];
    const bool g0m = (g == 0), g2m = (g == 2);
    const bool q0m = (q == 0), q1m = (q == 1);
    const bool qodd = (q & 1);
    const float cz = g2m ? (-2.f * L2E) : (-L2E);
    const float vs = g2m ? 2.f : 1.f;
    const float vo = g2m ? -1.f : 0.f;

    float h0 = 0.f, h1 = 0.f, h2 = 0.f, h3 = 0.f, cx = 0.f;
    float* outp = out + (size_t)b * 4 + q;

    float sxc[4], d2c[4], sxn[4], d2n[4];

    // ---- MFMA a quad from BUF; redistribute to (SXN, D2N) ----
    #define MFMAQ(BUF, SXN, D2N) do {                                       \
        asm volatile("s_waitcnt vmcnt(0)" ::: "memory");                    \
        f32x4 acc_ = {0.f, 0.f, 0.f, 0.f};                                  \
        float d2_ = 0.f;                                                    \
        _Pragma("unroll")                                                   \
        for (int ks_ = 0; ks_ < 16; ++ks_) {                                \
            float4 v0_ = *(const float4*)(BUF + ks_ * 2048 + lane * 16);    \
            float4 v1_ = *(const float4*)(BUF + ks_ * 2048 + 1024 + lane * 16); \
            float xf_[8] = {v0_.x, v0_.y, v0_.z, v0_.w,                     \
                            v1_.x, v1_.y, v1_.z, v1_.w};                    \
            float4 ka_ = *(const float4*)(kvl + ks_ * 128 + kb * 32);       \
            float4 kb2_ = *(const float4*)(kvl + ks_ * 128 + kb * 32 + 16); \
            float kvv_[8] = {ka_.x, ka_.y, ka_.z, ka_.w,                    \
                             kb2_.x, kb2_.y, kb2_.z, kb2_.w};               \
            _Pragma("unroll")                                               \
            for (int e_ = 0; e_ < 8; ++e_) {                                \
                float dx_ = xf_[e_] - kvv_[e_];                             \
                d2_ = fmaf(dx_, dx_, d2_);                                  \
            }                                                               \
            bf16x8 ah_, al_;                                                \
            _Pragma("unroll")                                               \
            for (int e_ = 0; e_ < 8; ++e_) {                                \
                __hip_bfloat16 hh_ = __float2bfloat16(xf_[e_]);             \
                ah_[e_] = bfbits(hh_);                                      \
                float rr_ = xf_[e_] - __bfloat162float(hh_);                \
                al_[e_] = bfbits(__float2bfloat16(rr_));                    \
            }                                                               \
            bf16x8 wh_ = *(const bf16x8*)(wld + ks_ * 1024 + lane * 16);    \
            bf16x8 wl_ = *(const bf16x8*)(wld + 16384 + ks_ * 1024 + lane * 16); \
            acc_ = __builtin_amdgcn_mfma_f32_16x16x32_bf16(ah_, wh_, acc_, 0, 0, 0); \
            acc_ = __builtin_amdgcn_mfma_f32_16x16x32_bf16(al_, wh_, acc_, 0, 0, 0); \
            acc_ = __builtin_amdgcn_mfma_f32_16x16x32_bf16(ah_, wl_, acc_, 0, 0, 0); \
        }                                                                   \
        d2_ += __shfl_xor(d2_, 16);                                         \
        d2_ += __shfl_xor(d2_, 32);                                         \
        const int bbv_ = lane >> 4;                                         \
        _Pragma("unroll")                                                   \
        for (int tt_ = 0; tt_ < 4; ++tt_) {                                 \
            float a0_ = __shfl(acc_[0], tt_ * 16 + s);                      \
            float a1_ = __shfl(acc_[1], tt_ * 16 + s);                      \
            float a2_ = __shfl(acc_[2], tt_ * 16 + s);                      \
            float a3_ = __shfl(acc_[3], tt_ * 16 + s);                      \
            (SXN)[tt_] = (bbv_ == 0) ? a0_ : (bbv_ == 1) ? a1_              \
                       : (bbv_ == 2) ? a2_ : a3_;                           \
            (D2N)[tt_] = __shfl(d2_, tt_ * 4 + bbv_);                       \
        }                                                                   \
    } while (0)

    // ---- one recurrence step (R13 math, verified) ----
    #define STEP(SX, D2X) do {                                              \
        float sxb = (SX) + bias;                                            \
        float gx  = __builtin_amdgcn_exp2f((D2X) * (-0.001f * L2E)) * INV2PI; \
        float dh0 = h0 - kh0, dh1 = h1 - kh1, dh2 = h2 - kh2, dh3 = h3 - kh3; \
        float d2h = fmaf(dh0, dh0, dh1 * dh1) + fmaf(dh2, dh2, dh3 * dh3);  \
        float uu = d2h * 1.0e-3f;                                           \
        float pa = fmaf(-0.16666667f, uu, 0.5f);                            \
        float pc = fmaf(-uu, pa, 1.0f);                                     \
        float gh = fmaf(-uu, pc, 1.0f);                                     \
        float gater = gh * gx;                                              \
        float p01 = fmaf(wh1, h1, fmaf(wh0, h0, sxb));                      \
        float p23 = fmaf(wh3, h3, wh2 * h2);                                \
        float pre = p01 + p23;                                              \
        float rev = fmaf(pre, gater, threv);                                \
        float cang = __builtin_amdgcn_cosf(__builtin_amdgcn_fractf(rev));   \
        float s1 = qperm<0xB1>(cang);                                       \
        float s2 = qperm<0x4E>(cang);                                       \
        float s3 = qperm<0x1B>(cang);                                       \
        float m23 = s2 * s3;                                                \
        float A  = q0m ? s1 : cang;                                         \
        float T1 = qodd ? s1 : 1.f;                                         \
        float T2 = q1m ? 1.f : m23;                                         \
        float z = A * T1 * T2;                                              \
        float e  = __builtin_amdgcn_exp2f(z * cz);                          \
        float sg = frcp(1.f + e);                                           \
        float val = fmaf(vs, sg, vo);                                       \
        float r4  = qperm<0x124>(val);                                      \
        float r8  = qperm<0x128>(val);                                      \
        float r12 = qperm<0x12C>(val);                                      \
        float f_ = g0m ? val : (g == 1) ? r4  : g2m ? r8  : r12;            \
        float i_ = g0m ? r12 : (g == 1) ? val : g2m ? r4  : r8;             \
        float u_ = g0m ? r8  : (g == 1) ? r12 : g2m ? val : r4;             \
        float o_ = g0m ? r4  : (g == 1) ? r8  : g2m ? r12 : val;            \
        float cn = fmaf(f_, cx, i_ * u_);                                   \
        float e2 = __builtin_amdgcn_exp2f(cn * (-2.f * L2E));               \
        float thc = (1.f - e2) * frcp(1.f + e2);                            \
        float hn = o_ * thc;                                                \
        cx = cn;                                                            \
        h0 = hn;                                                            \
        h1 = qperm<0xB1>(hn);                                               \
        h2 = qperm<0x4E>(hn);                                               \
        h3 = qperm<0x1B>(hn);                                               \
        if (g0m) *outp = hn;                                                \
        outp += BATCH * 4;                                                  \
    } while (0)

    #define RECUR4(SXA, D2A) do {                                           \
        STEP((SXA)[0], (D2A)[0]);                                           \
        STEP((SXA)[1], (D2A)[1]);                                           \
        STEP((SXA)[2], (D2A)[2]);                                           \
        STEP((SXA)[3], (D2A)[3]);                                           \
    } while (0)

    #define CPQ() do {                                                      \
        sxc[0] = sxn[0]; sxc[1] = sxn[1]; sxc[2] = sxn[2]; sxc[3] = sxn[3]; \
        d2c[0] = d2n[0]; d2c[1] = d2n[1]; d2c[2] = d2n[2]; d2c[3] = d2n[3]; \
    } while (0)

    // quad 0 (waits for all prologue staging)
    MFMAQ(xbA, sxc, d2c);

    // quads j=0..29: MFMA j+1, stage j+2, recur j
    for (int k = 0; k < 15; ++k) {
        MFMAQ(xbB, sxn, d2n);       // q(2k+1)
        XSTAGE(xbA, px); px += QSF; // q(2k+2)
        RECUR4(sxc, d2c);           // q(2k)
        CPQ();
        MFMAQ(xbA, sxn, d2n);       // q(2k+2)
        XSTAGE(xbB, px); px += QSF; // q(2k+3)
        RECUR4(sxc, d2c);           // q(2k+1)
        CPQ();
    }
    // tail: j=30 (MFMA q31, no stage), j=31
    MFMAQ(xbB, sxn, d2n);           // q31
    RECUR4(sxc, d2c);               // q30
    CPQ();
    RECUR4(sxc, d2c);               // q31

    if (g0m) {
        const size_t base = (size_t)T_STEPS * BATCH * 4;
        out[base + (size_t)b * 4 + q] = h0;
        out[base + BATCH * 4 + (size_t)b * 4 + q] = cx;
    }

    #undef XSTAGE
    #undef MFMAQ
    #undef STEP
    #undef RECUR4
    #undef CPQ
}

extern "C" void kernel_launch(void* const* d_in, const int* in_sizes, int n_in,
                              void* d_out, int out_size, void* d_ws, size_t ws_size,
                              hipStream_t stream) {
    const float* x   = (const float*)d_in[0];
    const float* Wf  = (const float*)d_in[1];
    const float* bf  = (const float*)d_in[2];
    const float* Wi  = (const float*)d_in[3];
    const float* bi  = (const float*)d_in[4];
    const float* Wu  = (const float*)d_in[5];
    const float* bu  = (const float*)d_in[6];
    const float* Wo  = (const float*)d_in[7];
    const float* bo  = (const float*)d_in[8];
    const float* thf = (const float*)d_in[9];
    const float* thi = (const float*)d_in[10];
    const float* thu = (const float*)d_in[11];
    const float* tho = (const float*)d_in[12];
    const float* kv  = (const float*)d_in[13];
    float* out = (float*)d_out;
    float* ws  = (float*)d_ws;   // needs 32KB for the W fragment table

    qlstm_p0<<<16, 64, 0, stream>>>(Wf, Wi, Wu, Wo, ws);
    qlstm_fused<<<128, 64, 0, stream>>>(x, Wf, Wi, Wu, Wo, bf, bi, bu, bo,
                                        thf, thi, thu, tho, kv, ws, out);
}

// Round 16
// 65.415 us; speedup vs baseline: 3.0433x; 1.7829x over previous
//
#include <hip/hip_runtime.h>
#include <hip/hip_bf16.h>

// QLSTM: quantum layer collapses to products of cosines.
// qlayer(x,th) with c_w = cos(x_w+th_w): out = [c1c2c3, c0c1, c0c1c2, c0c1c2c3]
//
// Phase 1 (MFMA, ~24us): sx = x·Wx via split-bf16 mfma_16x16x32; d2x exact f32.
// Phase 2 (latency chain): R15 trans-ectomy — z=Πcos ∈ [-1,1] so
//   sigmoid(z)/tanh(z) become short odd polys (no exp2/rcp); tanh(cn) via
//   Padé[5/4] (one rcp). On-chain trans: 5 -> 2 (v_cos + v_rcp).

#define T_STEPS 128
#define BATCH 512
#define IDIM 512

typedef __attribute__((ext_vector_type(8))) short bf16x8;
typedef __attribute__((ext_vector_type(4))) float f32x4;

#define INV2PI 0.15915494309189535f
#define L2E    1.4426950408889634f

static __device__ __forceinline__ short bfbits(__hip_bfloat16 h) {
    union { __hip_bfloat16 b; short s; } c; c.b = h; return c.s;
}

// DPP: quad_perm xor1=0xB1 xor2=0x4E xor3=0x1B; row_ror:n = 0x120|n.
template<int CTRL>
static __device__ __forceinline__ float qperm(float v) {
    return __int_as_float(__builtin_amdgcn_update_dpp(
        0, __float_as_int(v), CTRL, 0xF, 0xF, true));
}

static __device__ __forceinline__ float frcp(float v) {
    return __builtin_amdgcn_rcpf(v);
}

// ---------------- Phase 1 ----------------
// grid 512 blocks x 512 threads (8 waves). Each wave: one 16-row tile,
// K=512 in 16 steps of 32. A-frags loaded straight from global (f32),
// converted to bf16 hi/lo in registers. W bf16 hi/lo fragments in LDS.
__global__ __launch_bounds__(512) void qlstm_p1(
    const float* __restrict__ x,
    const float* __restrict__ Wf, const float* __restrict__ Wi,
    const float* __restrict__ Wu, const float* __restrict__ Wo,
    const float* __restrict__ kv,
    float* __restrict__ ws)
{
    __shared__ __align__(16) unsigned short whi[16 * 64 * 8];  // 16 KB [ks][lane][8]
    __shared__ __align__(16) unsigned short wlo[16 * 64 * 8];  // 16 KB
    __shared__ __align__(16) float kvl[IDIM];                  // 2 KB (linear copy)

    const int tid = threadIdx.x;

    // ---- stage W as bf16 hi/lo MFMA B-fragments ----
#pragma unroll
    for (int kk = 0; kk < 2; ++kk) {
        const int idx = tid + kk * 512;    // 0..1023 = (ks, lane)
        const int ks = idx >> 6;
        const int l  = idx & 63;
        const int c  = l & 15;             // output col n = g*4+q
        const int bq = l >> 4;             // k-chunk
        const int g  = c >> 2, q = c & 3;
        const float* Wsel = (g == 0) ? Wf : (g == 1) ? Wi : (g == 2) ? Wu : Wo;
        const float* src = Wsel + (size_t)q * 516 + ks * 32 + bq * 8;
        float4 w0 = *(const float4*)src;
        float4 w1 = *(const float4*)(src + 4);
        float wf8[8] = {w0.x, w0.y, w0.z, w0.w, w1.x, w1.y, w1.z, w1.w};
        unsigned short h8[8], l8[8];
#pragma unroll
        for (int j = 0; j < 8; ++j) {
            __hip_bfloat16 h = __float2bfloat16(wf8[j]);
            h8[j] = (unsigned short)bfbits(h);
            float r = wf8[j] - __bfloat162float(h);
            l8[j] = (unsigned short)bfbits(__float2bfloat16(r));
        }
        *(uint4*)&whi[idx * 8] = *(const uint4*)h8;
        *(uint4*)&wlo[idx * 8] = *(const uint4*)l8;
    }
    if (tid < 128)
        *(float4*)&kvl[tid * 4] = *(const float4*)(kv + tid * 4);
    __syncthreads();

    const int lane  = tid & 63;
    const int wave  = tid >> 6;
    const int row16 = lane & 15;          // A row within tile
    const int kb    = lane >> 4;          // k-chunk 0..3
    const int rowbase = (blockIdx.x * 8 + wave) * 16;

    const float* xp = x + (size_t)(rowbase + row16) * IDIM + kb * 8;

    f32x4 acc = {0.f, 0.f, 0.f, 0.f};
    float d2 = 0.f;

    float4 pA[2], pB[2];
    pA[0] = *(const float4*)(xp);       pB[0] = *(const float4*)(xp + 4);
    pA[1] = *(const float4*)(xp + 32);  pB[1] = *(const float4*)(xp + 36);

#pragma unroll
    for (int ks = 0; ks < 16; ++ks) {
        const int sl = ks & 1;
        float xf[8] = {pA[sl].x, pA[sl].y, pA[sl].z, pA[sl].w,
                       pB[sl].x, pB[sl].y, pB[sl].z, pB[sl].w};
        if (ks + 2 < 16) {   // refill the slot we just drained
            pA[sl] = *(const float4*)(xp + (ks + 2) * 32);
            pB[sl] = *(const float4*)(xp + (ks + 2) * 32 + 4);
        }

        // exact-f32 distance accumulation
        const float* kvp = &kvl[ks * 32 + kb * 8];
        float4 kva = *(const float4*)kvp;
        float4 kvb = *(const float4*)(kvp + 4);
        float kvv[8] = {kva.x, kva.y, kva.z, kva.w, kvb.x, kvb.y, kvb.z, kvb.w};
#pragma unroll
        for (int j = 0; j < 8; ++j) {
            float dx = xf[j] - kvv[j];
            d2 = fmaf(dx, dx, d2);
        }

        // split bf16 A-fragments
        bf16x8 ah, al;
#pragma unroll
        for (int j = 0; j < 8; ++j) {
            __hip_bfloat16 h = __float2bfloat16(xf[j]);
            ah[j] = bfbits(h);
            float r = xf[j] - __bfloat162float(h);
            al[j] = bfbits(__float2bfloat16(r));
        }

        bf16x8 wh = *(const bf16x8*)&whi[(ks * 64 + lane) * 8];
        bf16x8 wl = *(const bf16x8*)&wlo[(ks * 64 + lane) * 8];

        acc = __builtin_amdgcn_mfma_f32_16x16x32_bf16(ah, wh, acc, 0, 0, 0);
        acc = __builtin_amdgcn_mfma_f32_16x16x32_bf16(al, wh, acc, 0, 0, 0);
        acc = __builtin_amdgcn_mfma_f32_16x16x32_bf16(ah, wl, acc, 0, 0, 0);
    }

    // reduce d2 over the 4 kb-lanes of each row (lane bits 4,5)
    d2 += __shfl_xor(d2, 16);
    d2 += __shfl_xor(d2, 32);

    // epilogue: C layout col = lane&15, row = (lane>>4)*4 + reg
    const int ccol = lane & 15;
    const int crow = (lane >> 4) * 4;
#pragma unroll
    for (int j = 0; j < 4; ++j)
        ws[(size_t)(rowbase + crow + j) * 20 + ccol] = acc[j];
    if (lane < 16)
        ws[(size_t)(rowbase + lane) * 20 + 16] = d2;
}

// ---------------- Phase 2 ----------------
// grid 128 blocks x 64 threads; 16 lanes per batch element b.
// lane s = g*4+q (g: gate f/i/u/o, q: wire). hx kept in xor-relative order.
// 4-deep ws prefetch ring; ALL cross-lane via DPP; R15 poly activations:
//   val(z) = fmaf(z, c0+c1 r+c2 r^2+c3 r^3, off), r=z^2
//     sigmoid lanes: c=(.250001,-.020794,.001852,0), off=.5   (err<=2e-5)
//     tanh-u lanes:  c=(.999892,-.330836,.119567,-.027029), off=0 (err<=1.2e-4)
//   tanh(cn) = cn(945+105r+r^2) / (945+420r+15r^2), r=cn^2    (err<=1.3e-4)
__global__ __launch_bounds__(64) void qlstm_p2(
    const float* __restrict__ ws,
    const float* __restrict__ Wf, const float* __restrict__ Wi,
    const float* __restrict__ Wu, const float* __restrict__ Wo,
    const float* __restrict__ bf, const float* __restrict__ bi,
    const float* __restrict__ bu, const float* __restrict__ bo,
    const float* __restrict__ thf, const float* __restrict__ thi,
    const float* __restrict__ thu, const float* __restrict__ tho,
    const float* __restrict__ kv,
    float* __restrict__ out)
{
    const int lane = threadIdx.x;                 // 0..63
    const int b    = blockIdx.x * 4 + (lane >> 4);
    const int s    = lane & 15;
    const int g    = s >> 2;
    const int q    = s & 3;

    const float* W  = (g == 0) ? Wf  : (g == 1) ? Wi  : (g == 2) ? Wu  : Wo;
    const float* bb = (g == 0) ? bf  : (g == 1) ? bi  : (g == 2) ? bu  : bo;
    const float* th = (g == 0) ? thf : (g == 1) ? thi : (g == 2) ? thu : tho;

    // Wh row and kv tail in xor-relative order (index k holds element q^k)
    const float wh0 = W[(size_t)q * 516 + 512 + (q ^ 0)];
    const float wh1 = W[(size_t)q * 516 + 512 + (q ^ 1)];
    const float wh2 = W[(size_t)q * 516 + 512 + (q ^ 2)];
    const float wh3 = W[(size_t)q * 516 + 512 + (q ^ 3)];
    const float bias  = bb[q];
    const float threv = th[q] * INV2PI;           // theta/2pi
    const float kh0 = kv[512 + (q ^ 0)];
    const float kh1 = kv[512 + (q ^ 1)];
    const float kh2 = kv[512 + (q ^ 2)];
    const float kh3 = kv[512 + (q ^ 3)];

    const bool g0m = (g == 0), g2m = (g == 2);
    const bool q0m = (q == 0), q1m = (q == 1);
    const bool qodd = (q & 1);

    // per-lane activation poly coefficients (val = fmaf(z, P3(z^2), off))
    const float c0 = g2m ? 0.999892f  : 0.250001f;
    const float c1 = g2m ? -0.330836f : -0.020794f;
    const float c2 = g2m ? 0.119567f  : 0.001852f;
    const float c3 = g2m ? -0.027029f : 0.f;
    const float off = g2m ? 0.f : 0.5f;

    float h0 = 0.f, h1 = 0.f, h2 = 0.f, h3 = 0.f, cx = 0.f;

    // per-lane ws addresses: sx at +s, d2 at +16 (broadcast within the 16)
    #define WS_SX(t) ws[((size_t)(t) * BATCH + b) * 20 + s]
    #define WS_D2(t) ws[((size_t)(t) * BATCH + b) * 20 + 16]

    // prefetch ring: slots for steps t .. t+3
    float cs0 = WS_SX(0), cd0 = WS_D2(0);
    float cs1 = WS_SX(1), cd1 = WS_D2(1);
    float cs2 = WS_SX(2), cd2 = WS_D2(2);
    float cs3 = WS_SX(3), cd3 = WS_D2(3);

    #define STEP(SX, D2X, t) do {                                          \
        /* off-chain (data-only) terms */                                   \
        float sxb = (SX) + bias;                                           \
        float gx  = __builtin_amdgcn_exp2f((D2X) * (-0.001f * L2E)) * INV2PI; \
        /* on-chain: d2h -> gh (2 fma) -> gate -> rev -> cos */            \
        float dh0 = h0 - kh0, dh1 = h1 - kh1, dh2 = h2 - kh2, dh3 = h3 - kh3; \
        float d2h = fmaf(dh0, dh0, dh1 * dh1) + fmaf(dh2, dh2, dh3 * dh3); \
        float uu = d2h * 1.0e-3f;                                          \
        float gh = fmaf(uu, fmaf(0.5f, uu, -1.f), 1.f); /* e^-uu err<=1e-5 */ \
        float gater = gh * gx;                                             \
        float p01 = fmaf(wh1, h1, fmaf(wh0, h0, sxb));                     \
        float p23 = fmaf(wh3, h3, wh2 * h2);                               \
        float pre = p01 + p23;                                             \
        float rev = fmaf(pre, gater, threv);                               \
        float cang = __builtin_amdgcn_cosf(__builtin_amdgcn_fractf(rev));  \
        float s1 = qperm<0xB1>(cang);                                      \
        float s2 = qperm<0x4E>(cang);                                      \
        float s3 = qperm<0x1B>(cang);                                      \
        float m23 = s2 * s3;                                               \
        float A  = q0m ? s1 : cang;                                        \
        float T1 = qodd ? s1 : 1.f;                                        \
        float T2 = q1m ? 1.f : m23;                                        \
        float z = A * T1 * T2;                                             \
        /* activation via odd poly (no trans) */                           \
        float zr = z * z;                                                  \
        float P  = fmaf(zr, fmaf(zr, fmaf(zr, c3, c2), c1), c0);           \
        float val = fmaf(z, P, off);                                       \
        float r4  = qperm<0x124>(val);  /* row_ror:4  -> gate g-1 */       \
        float r8  = qperm<0x128>(val);  /* row_ror:8  -> gate g-2 */       \
        float r12 = qperm<0x12C>(val);  /* row_ror:12 -> gate g-3 */       \
        float f_ = g0m ? val : (g == 1) ? r4  : g2m ? r8  : r12;           \
        float i_ = g0m ? r12 : (g == 1) ? val : g2m ? r4  : r8;            \
        float u_ = g0m ? r8  : (g == 1) ? r12 : g2m ? val : r4;            \
        float o_ = g0m ? r4  : (g == 1) ? r8  : g2m ? r12 : val;           \
        float cn = fmaf(f_, cx, i_ * u_);                                  \
        /* tanh(cn) via Pade[5/4] (one rcp) */                             \
        float cr = cn * cn;                                                \
        float num = cn * fmaf(cr, cr + 105.f, 945.f);                      \
        float den = fmaf(cr, fmaf(cr, 15.f, 420.f), 945.f);                \
        float thc = num * frcp(den);                                       \
        float hn = o_ * thc;                                               \
        cx = cn;                                                           \
        h0 = hn;                                                           \
        h1 = qperm<0xB1>(hn);                                              \
        h2 = qperm<0x4E>(hn);                                              \
        h3 = qperm<0x1B>(hn);                                              \
        if (g0m) out[(size_t)(t) * (BATCH * 4) + b * 4 + q] = hn;          \
    } while (0)

    for (int tb = 0; tb < T_STEPS / 4; ++tb) {
        const int t0 = tb * 4;
        float ns0 = 0.f, nd0 = 0.f, ns1 = 0.f, nd1 = 0.f;
        float ns2 = 0.f, nd2 = 0.f, ns3 = 0.f, nd3 = 0.f;
        if (tb < T_STEPS / 4 - 1) {       // issue next 4 steps' loads NOW
            ns0 = WS_SX(t0 + 4); nd0 = WS_D2(t0 + 4);
            ns1 = WS_SX(t0 + 5); nd1 = WS_D2(t0 + 5);
            ns2 = WS_SX(t0 + 6); nd2 = WS_D2(t0 + 6);
            ns3 = WS_SX(t0 + 7); nd3 = WS_D2(t0 + 7);
        }
        STEP(cs0, cd0, t0 + 0);
        STEP(cs1, cd1, t0 + 1);
        STEP(cs2, cd2, t0 + 2);
        STEP(cs3, cd3, t0 + 3);
        cs0 = ns0; cd0 = nd0; cs1 = ns1; cd1 = nd1;
        cs2 = ns2; cd2 = nd2; cs3 = ns3; cd3 = nd3;
    }

    #undef STEP
    #undef WS_SX
    #undef WS_D2

    if (g0m) {
        const size_t base = (size_t)T_STEPS * BATCH * 4;
        out[base + b * 4 + q] = h0;
        out[base + BATCH * 4 + b * 4 + q] = cx;
    }
}

extern "C" void kernel_launch(void* const* d_in, const int* in_sizes, int n_in,
                              void* d_out, int out_size, void* d_ws, size_t ws_size,
                              hipStream_t stream) {
    const float* x   = (const float*)d_in[0];
    const float* Wf  = (const float*)d_in[1];
    const float* bf  = (const float*)d_in[2];
    const float* Wi  = (const float*)d_in[3];
    const float* bi  = (const float*)d_in[4];
    const float* Wu  = (const float*)d_in[5];
    const float* bu  = (const float*)d_in[6];
    const float* Wo  = (const float*)d_in[7];
    const float* bo  = (const float*)d_in[8];
    const float* thf = (const float*)d_in[9];
    const float* thi = (const float*)d_in[10];
    const float* thu = (const float*)d_in[11];
    const float* tho = (const float*)d_in[12];
    const float* kv  = (const float*)d_in[13];
    float* out = (float*)d_out;
    float* ws  = (float*)d_ws;   // needs 65536*20*4 = 5.24 MB

    qlstm_p1<<<512, 512, 0, stream>>>(x, Wf, Wi, Wu, Wo, kv, ws);
    qlstm_p2<<<128, 64, 0, stream>>>(ws, Wf, Wi, Wu, Wo, bf, bi, bu, bo,
                                     thf, thi, thu, tho, kv, out);
}

// Round 17
// 41.640 us; speedup vs baseline: 4.7808x; 1.5710x over previous
//
#include <hip/hip_runtime.h>
#include <hip/hip_bf16.h>

// QLSTM fused intra-block producer-consumer (R16).
// qlayer(x,th) with c_w = cos(x_w+th_w): out = [c1c2c3, c0c1, c0c1c2, c0c1c2c3]
//
// 128 blocks x 256 threads (4 waves, ~1 block/CU -> wave-per-SIMD).
//   wave 0  = consumer: R15 recurrence chain for 4 batch elements,
//             consuming (sx,d2) t-quads from an 8-slot LDS ring.
//   waves 1-3 = producers: p1's verified split-bf16 MFMA pipeline, one
//             16x16 tile (= 4 t-steps x 4 batches) per quad, round-robin.
// Sync: LDS flags + progress counter, WORKGROUP-scope acquire/release only
// (no cross-block, no agent scope — R11/R13 failure modes avoided).
// m114: MFMA waves and the VALU chain wave co-schedule on one CU.

#define T_STEPS 128
#define BATCH 512
#define IDIM 512

typedef __attribute__((ext_vector_type(8))) short bf16x8;
typedef __attribute__((ext_vector_type(4))) float f32x4;

#define INV2PI 0.15915494309189535f
#define L2E    1.4426950408889634f

static __device__ __forceinline__ short bfbits(__hip_bfloat16 h) {
    union { __hip_bfloat16 b; short s; } c; c.b = h; return c.s;
}

// DPP: quad_perm xor1=0xB1 xor2=0x4E xor3=0x1B; row_ror:n = 0x120|n.
template<int CTRL>
static __device__ __forceinline__ float qperm(float v) {
    return __int_as_float(__builtin_amdgcn_update_dpp(
        0, __float_as_int(v), CTRL, 0xF, 0xF, true));
}

static __device__ __forceinline__ float frcp(float v) {
    return __builtin_amdgcn_rcpf(v);
}

__global__ __launch_bounds__(256, 1) void qlstm_fused(
    const float* __restrict__ x,
    const float* __restrict__ Wf, const float* __restrict__ Wi,
    const float* __restrict__ Wu, const float* __restrict__ Wo,
    const float* __restrict__ bf, const float* __restrict__ bi,
    const float* __restrict__ bu, const float* __restrict__ bo,
    const float* __restrict__ thf, const float* __restrict__ thi,
    const float* __restrict__ thu, const float* __restrict__ tho,
    const float* __restrict__ kv,
    float* __restrict__ out)
{
    __shared__ __align__(16) unsigned short whi[16 * 64 * 8];  // 16 KB
    __shared__ __align__(16) unsigned short wlo[16 * 64 * 8];  // 16 KB
    __shared__ __align__(16) float kvl[IDIM];                  // 2 KB
    __shared__ float sxs[8][16][17];                           // ring: sx tiles
    __shared__ float d2s[8][16];                               // ring: d2 rows
    __shared__ int   flags[32];                                // quad ready
    __shared__ int   done;                                     // quads consumed

    const int tid  = threadIdx.x;   // 0..255
    const int wave = tid >> 6;      // 0..3
    const int lane = tid & 63;
    const int blk  = blockIdx.x;

    // ---- stage W as bf16 hi/lo MFMA B-fragments (1024 entries, 4/thread) ----
#pragma unroll
    for (int kk = 0; kk < 4; ++kk) {
        const int idx = tid + kk * 256;    // 0..1023 = (ks, lane)
        const int ks = idx >> 6;
        const int l  = idx & 63;
        const int c  = l & 15;
        const int bq = l >> 4;
        const int g  = c >> 2, q = c & 3;
        const float* Wsel = (g == 0) ? Wf : (g == 1) ? Wi : (g == 2) ? Wu : Wo;
        const float* src = Wsel + (size_t)q * 516 + ks * 32 + bq * 8;
        float4 w0 = *(const float4*)src;
        float4 w1 = *(const float4*)(src + 4);
        float wf8[8] = {w0.x, w0.y, w0.z, w0.w, w1.x, w1.y, w1.z, w1.w};
        unsigned short h8[8], l8[8];
#pragma unroll
        for (int j = 0; j < 8; ++j) {
            __hip_bfloat16 h = __float2bfloat16(wf8[j]);
            h8[j] = (unsigned short)bfbits(h);
            float r = wf8[j] - __bfloat162float(h);
            l8[j] = (unsigned short)bfbits(__float2bfloat16(r));
        }
        *(uint4*)&whi[idx * 8] = *(const uint4*)h8;
        *(uint4*)&wlo[idx * 8] = *(const uint4*)l8;
    }
    if (tid < 128)
        *(float4*)&kvl[tid * 4] = *(const float4*)(kv + tid * 4);
    if (tid < 32) flags[tid] = 0;
    if (tid == 32) done = 0;
    __syncthreads();   // ONLY barrier; roles diverge after this

    if (wave != 0) {
        // ================= producers (waves 1..3) =================
        const int row16 = lane & 15;        // tile row: tt*4+bb
        const int kb    = lane >> 4;        // k-chunk
        const int crow  = (lane >> 4) * 4;  // C-frag rows
        const int ccol  = lane & 15;        // C-frag col

        for (int j = wave - 1; j < 32; j += 3) {
            // ring space: slot j&7 free once consumer passed quad j-8
            while (__hip_atomic_load(&done, __ATOMIC_ACQUIRE,
                                     __HIP_MEMORY_SCOPE_WORKGROUP) < j - 7)
                __builtin_amdgcn_s_sleep(2);

            const float* px = x
                + ((size_t)(4 * j + (row16 >> 2)) * BATCH + blk * 4 + (row16 & 3)) * IDIM
                + kb * 8;

            float4 pA[4], pB[4];
#pragma unroll
            for (int i = 0; i < 4; ++i) {
                pA[i] = *(const float4*)(px + i * 32);
                pB[i] = *(const float4*)(px + i * 32 + 4);
            }
            f32x4 acc = {0.f, 0.f, 0.f, 0.f};
            float d2 = 0.f;

#pragma unroll
            for (int ks = 0; ks < 16; ++ks) {
                const int sl = ks & 3;
                float xf[8] = {pA[sl].x, pA[sl].y, pA[sl].z, pA[sl].w,
                               pB[sl].x, pB[sl].y, pB[sl].z, pB[sl].w};
                if (ks + 4 < 16) {   // 4-deep prefetch
                    pA[sl] = *(const float4*)(px + (ks + 4) * 32);
                    pB[sl] = *(const float4*)(px + (ks + 4) * 32 + 4);
                }
                const float* kvp = &kvl[ks * 32 + kb * 8];
                float4 kva = *(const float4*)kvp;
                float4 kvb = *(const float4*)(kvp + 4);
                float kvv[8] = {kva.x, kva.y, kva.z, kva.w,
                                kvb.x, kvb.y, kvb.z, kvb.w};
#pragma unroll
                for (int e = 0; e < 8; ++e) {
                    float dx = xf[e] - kvv[e];
                    d2 = fmaf(dx, dx, d2);
                }
                bf16x8 ah, al;
#pragma unroll
                for (int e = 0; e < 8; ++e) {
                    __hip_bfloat16 h = __float2bfloat16(xf[e]);
                    ah[e] = bfbits(h);
                    float r = xf[e] - __bfloat162float(h);
                    al[e] = bfbits(__float2bfloat16(r));
                }
                bf16x8 wh = *(const bf16x8*)&whi[(ks * 64 + lane) * 8];
                bf16x8 wl = *(const bf16x8*)&wlo[(ks * 64 + lane) * 8];
                acc = __builtin_amdgcn_mfma_f32_16x16x32_bf16(ah, wh, acc, 0, 0, 0);
                acc = __builtin_amdgcn_mfma_f32_16x16x32_bf16(al, wh, acc, 0, 0, 0);
                acc = __builtin_amdgcn_mfma_f32_16x16x32_bf16(ah, wl, acc, 0, 0, 0);
            }

            d2 += __shfl_xor(d2, 16);
            d2 += __shfl_xor(d2, 32);

            const int slot = j & 7;
#pragma unroll
            for (int e = 0; e < 4; ++e)
                sxs[slot][crow + e][ccol] = acc[e];
            if (lane < 16) d2s[slot][lane] = d2;
            // release: drains the ds_writes above before flag becomes visible
            __hip_atomic_store(&flags[j], 1, __ATOMIC_RELEASE,
                               __HIP_MEMORY_SCOPE_WORKGROUP);
        }
    } else {
        // ================= consumer (wave 0) =================
        const int s   = lane & 15;
        const int g   = s >> 2;
        const int q   = s & 3;
        const int b_l = lane >> 4;
        const int b   = blk * 4 + b_l;

        const float* W   = (g == 0) ? Wf  : (g == 1) ? Wi  : (g == 2) ? Wu  : Wo;
        const float* bb_ = (g == 0) ? bf  : (g == 1) ? bi  : (g == 2) ? bu  : bo;
        const float* th  = (g == 0) ? thf : (g == 1) ? thi : (g == 2) ? thu : tho;

        const float wh0 = W[(size_t)q * 516 + 512 + (q ^ 0)];
        const float wh1 = W[(size_t)q * 516 + 512 + (q ^ 1)];
        const float wh2 = W[(size_t)q * 516 + 512 + (q ^ 2)];
        const float wh3 = W[(size_t)q * 516 + 512 + (q ^ 3)];
        const float bias  = bb_[q];
        const float threv = th[q] * INV2PI;
        const float kh0 = kv[512 + (q ^ 0)];
        const float kh1 = kv[512 + (q ^ 1)];
        const float kh2 = kv[512 + (q ^ 2)];
        const float kh3 = kv[512 + (q ^ 3)];

        const bool g0m = (g == 0), g2m = (g == 2);
        const bool q0m = (q == 0), q1m = (q == 1);
        const bool qodd = (q & 1);

        const float c0 = g2m ? 0.999892f  : 0.250001f;
        const float c1 = g2m ? -0.330836f : -0.020794f;
        const float c2 = g2m ? 0.119567f  : 0.001852f;
        const float c3 = g2m ? -0.027029f : 0.f;
        const float off = g2m ? 0.f : 0.5f;

        float h0 = 0.f, h1 = 0.f, h2 = 0.f, h3 = 0.f, cx = 0.f;

        #define STEP(SX, D2X, t) do {                                          \
            float sxb = (SX) + bias;                                           \
            float gx  = __builtin_amdgcn_exp2f((D2X) * (-0.001f * L2E)) * INV2PI; \
            float dh0 = h0 - kh0, dh1 = h1 - kh1, dh2 = h2 - kh2, dh3 = h3 - kh3; \
            float d2h = fmaf(dh0, dh0, dh1 * dh1) + fmaf(dh2, dh2, dh3 * dh3); \
            float uu = d2h * 1.0e-3f;                                          \
            float gh = fmaf(uu, fmaf(0.5f, uu, -1.f), 1.f);                    \
            float gater = gh * gx;                                             \
            float p01 = fmaf(wh1, h1, fmaf(wh0, h0, sxb));                     \
            float p23 = fmaf(wh3, h3, wh2 * h2);                               \
            float pre = p01 + p23;                                             \
            float rev = fmaf(pre, gater, threv);                               \
            float cang = __builtin_amdgcn_cosf(__builtin_amdgcn_fractf(rev));  \
            float s1 = qperm<0xB1>(cang);                                      \
            float s2 = qperm<0x4E>(cang);                                      \
            float s3 = qperm<0x1B>(cang);                                      \
            float m23 = s2 * s3;                                               \
            float A  = q0m ? s1 : cang;                                        \
            float T1 = qodd ? s1 : 1.f;                                        \
            float T2 = q1m ? 1.f : m23;                                        \
            float z = A * T1 * T2;                                             \
            float zr = z * z;                                                  \
            float P  = fmaf(zr, fmaf(zr, fmaf(zr, c3, c2), c1), c0);           \
            float val = fmaf(z, P, off);                                       \
            float r4  = qperm<0x124>(val);                                     \
            float r8  = qperm<0x128>(val);                                     \
            float r12 = qperm<0x12C>(val);                                     \
            float f_ = g0m ? val : (g == 1) ? r4  : g2m ? r8  : r12;           \
            float i_ = g0m ? r12 : (g == 1) ? val : g2m ? r4  : r8;            \
            float u_ = g0m ? r8  : (g == 1) ? r12 : g2m ? val : r4;            \
            float o_ = g0m ? r4  : (g == 1) ? r8  : g2m ? r12 : val;           \
            float cn = fmaf(f_, cx, i_ * u_);                                  \
            float cr = cn * cn;                                                \
            float num = cn * fmaf(cr, cr + 105.f, 945.f);                      \
            float den = fmaf(cr, fmaf(cr, 15.f, 420.f), 945.f);                \
            float thc = num * frcp(den);                                       \
            float hn = o_ * thc;                                               \
            cx = cn;                                                           \
            h0 = hn;                                                           \
            h1 = qperm<0xB1>(hn);                                              \
            h2 = qperm<0x4E>(hn);                                              \
            h3 = qperm<0x1B>(hn);                                              \
            if (g0m) out[(size_t)(t) * (BATCH * 4) + b * 4 + q] = hn;          \
        } while (0)

        for (int j = 0; j < 32; ++j) {
            while (__hip_atomic_load(&flags[j], __ATOMIC_ACQUIRE,
                                     __HIP_MEMORY_SCOPE_WORKGROUP) == 0)
                __builtin_amdgcn_s_sleep(1);
            const int slot = j & 7;
            float sx0 = sxs[slot][b_l][s],      dd0 = d2s[slot][b_l];
            float sx1 = sxs[slot][4 + b_l][s],  dd1 = d2s[slot][4 + b_l];
            float sx2 = sxs[slot][8 + b_l][s],  dd2 = d2s[slot][8 + b_l];
            float sx3 = sxs[slot][12 + b_l][s], dd3 = d2s[slot][12 + b_l];
            STEP(sx0, dd0, 4 * j + 0);
            STEP(sx1, dd1, 4 * j + 1);
            STEP(sx2, dd2, 4 * j + 2);
            STEP(sx3, dd3, 4 * j + 3);
            __hip_atomic_store(&done, j + 1, __ATOMIC_RELEASE,
                               __HIP_MEMORY_SCOPE_WORKGROUP);
        }
        #undef STEP

        if (g0m) {
            const size_t base = (size_t)T_STEPS * BATCH * 4;
            out[base + (size_t)b * 4 + q] = h0;
            out[base + BATCH * 4 + (size_t)b * 4 + q] = cx;
        }
    }
}

extern "C" void kernel_launch(void* const* d_in, const int* in_sizes, int n_in,
                              void* d_out, int out_size, void* d_ws, size_t ws_size,
                              hipStream_t stream) {
    const float* x   = (const float*)d_in[0];
    const float* Wf  = (const float*)d_in[1];
    const float* bf  = (const float*)d_in[2];
    const float* Wi  = (const float*)d_in[3];
    const float* bi  = (const float*)d_in[4];
    const float* Wu  = (const float*)d_in[5];
    const float* bu  = (const float*)d_in[6];
    const float* Wo  = (const float*)d_in[7];
    const float* bo  = (const float*)d_in[8];
    const float* thf = (const float*)d_in[9];
    const float* thi = (const float*)d_in[10];
    const float* thu = (const float*)d_in[11];
    const float* tho = (const float*)d_in[12];
    const float* kv  = (const float*)d_in[13];
    float* out = (float*)d_out;

    qlstm_fused<<<128, 256, 0, stream>>>(x, Wf, Wi, Wu, Wo, bf, bi, bu, bo,
                                         thf, thi, thu, tho, kv, out);
}